// Round 10
// baseline (107.130 us; speedup 1.0000x reference)
//
#include <hip/hip_runtime.h>

// ExemplarNoAttention: logits[b,c] = log( sum_{e: label[e]==c} exp(-beta*d2[b,e]) + eps )
// d2[b,e] = ||x_b||^2 + ||e_e||^2 - 2<x_b,e_e>, clamped >= 0; beta = softplus(beta_raw).
//
// Round 10 = R9 verbatim, ONE variable: chunk split 98x512 -> 196x256.
// Rationale: OccupancyPercent ~40-55% was the invariant across ALL main variants
// (R3-R9) while four different memory-path rewrites were neutral. The grid
// (1568 blocks = 6.1/CU) caps occupancy below the resource limit (8 blocks/CU by
// LDS/VGPR). 3136 blocks = 12.25/CU lets the scheduler keep ~8 blocks resident
// -> 2-3x more independent wave-chains per SIMD to hide the subtile dependency
// chain (ds_read -> MFMA1 -> exp -> MFMA2).
// Everything else R9: LDS double-buffered register staging, onehot-MFMA
// segment-sum (zero in-loop atomics), contention-free private partial stores,
// reduce+log finalize. Harness floor ~60 us (268 MB d_ws poison fill + restores).

#define NB      1024
#define NE      50000
#define NE_PAD  50176    // 196 chunks * 256
#define NCHUNK  196
#define CROWS   256      // e-rows per chunk
#define KD      64
#define NC      10
#define SROWS   64       // e-rows per stage
#define NSTAGE  4        // 256 / SROWS
#define LROW    72       // padded LDS row stride in halfs (144 B)

using half8   = __attribute__((ext_vector_type(8))) _Float16;  // 16x16x32 A/B frag (4 VGPRs)
using half4v  = __attribute__((ext_vector_type(4))) _Float16;  // 16x16x16 A/B frag (2 VGPRs)
using floatx4 = __attribute__((ext_vector_type(4))) float;

__device__ __forceinline__ float softplus_f(float x) {
  return (x > 20.f) ? x : log1pf(__expf(x));
}

// ---------------------------------------------------------------------------
// prep: cast x/exemplars to fp16, cb = -beta*||x||^2, ce = -beta*||e||^2,
// padded labels. 16 lanes/row, 16 rows/block, 3200 blocks.
// Pad rows [NE, NE_PAD): ex_h = 0, ce = -1e30 (=> sim exactly 0), label 0.
// ---------------------------------------------------------------------------
__global__ __launch_bounds__(256) void prep_kernel(
    const float* __restrict__ x, const float* __restrict__ ex,
    const int* __restrict__ labels, const float* __restrict__ beta_raw,
    _Float16* __restrict__ ex_h, float* __restrict__ ce,
    _Float16* __restrict__ x_h, float* __restrict__ cb,
    int* __restrict__ lab_pad)
{
  const int tid = threadIdx.x;
  const float beta = softplus_f(beta_raw[0]);

  const int row = blockIdx.x * 16 + (tid >> 4);  // 3200*16 = 51200 = NE_PAD + NB
  const int l16 = tid & 15;

  if (row < NE_PAD) {
    float4 v = make_float4(0.f, 0.f, 0.f, 0.f);
    if (row < NE) v = ((const float4*)ex)[row * 16 + l16];
    half4v hv = { (_Float16)v.x, (_Float16)v.y, (_Float16)v.z, (_Float16)v.w };
    *(half4v*)(ex_h + (size_t)row * KD + l16 * 4) = hv;
    float s = v.x*v.x + v.y*v.y + v.z*v.z + v.w*v.w;
    #pragma unroll
    for (int m = 1; m < 16; m <<= 1) s += __shfl_xor(s, m, 64);
    if (l16 == 0) ce[row] = (row < NE) ? (-beta * s) : -1e30f;
    if (l16 == 1) lab_pad[row] = (row < NE) ? labels[row] : 0;
  } else {
    const int rx = row - NE_PAD;  // [0, NB)
    float4 v = ((const float4*)x)[rx * 16 + l16];
    half4v hv = { (_Float16)v.x, (_Float16)v.y, (_Float16)v.z, (_Float16)v.w };
    *(half4v*)(x_h + (size_t)rx * KD + l16 * 4) = hv;
    float s = v.x*v.x + v.y*v.y + v.z*v.z + v.w*v.w;
    #pragma unroll
    for (int m = 1; m < 16; m <<= 1) s += __shfl_xor(s, m, 64);
    if (l16 == 0) cb[rx] = -beta * s;
  }
}

// ---------------------------------------------------------------------------
// main: grid (16 btiles, 196 chunks of 256 e-rows), block = 4 waves. Wave w owns
// batch cols [btile*64+16w, +16) (B-frags from x_h, loaded once). Per stage
// (64 e-rows): prefetch next stage global->regs, compute 4 subtiles from LDS
// buf, barrier, write regs->other buf, barrier.  (R6/R9 structure.)
// Subtile: MFMA1 16x16x32 -> d[e][b]; p = exp(min(2*beta*d + cb + ce, 0)) fp16
//   (= 16x16x16 B-frag); MFMA2 vs onehot labels -> acc[c][b] in AGPRs.
// Flush: plain coalesced stores of the block's 640-float partial into
//   part[chunk][(bm+l15)*10 + c] -- zero atomics, zero contention.
// ---------------------------------------------------------------------------
__global__ __launch_bounds__(256) void main_kernel(
    const _Float16* __restrict__ ex_h, const float* __restrict__ ce,
    const _Float16* __restrict__ x_h, const float* __restrict__ cb,
    const int* __restrict__ lab_pad, const float* __restrict__ beta_raw,
    float* __restrict__ part)
{
  __shared__ _Float16 Ah[2][SROWS * LROW];
  __shared__ float    Ce[2][SROWS];
  __shared__ int      Lb[2][SROWS];

  const int tid  = threadIdx.x;
  const int wave = tid >> 6;
  const int lane = tid & 63;
  const int l15  = lane & 15;
  const int quad = lane >> 4;

  const int btile = blockIdx.x;
  const int chunk = blockIdx.y;
  const int e0    = chunk * CROWS;
  const int bm    = btile * 64 + wave * 16;

  const float beta = softplus_f(beta_raw[0]);
  const float s2 = 2.f * beta;

  // x B-frags: B[k=quad*8+j][n=l15] -> x_h row-major, loaded once per wave.
  const half8* xrow = (const half8*)(x_h + (size_t)(bm + l15) * KD);
  const half8 bx0 = xrow[quad];
  const half8 bx1 = xrow[quad + 4];
  const float cbl = cb[bm + l15];

  // stage-load lane constants: thread t moves 32 B of row (t>>2), halfs [(t&3)*16..)
  const int srow = tid >> 2;
  const int scol = tid & 3;
  const _Float16* gsrc = ex_h + (size_t)(e0 + srow) * KD + scol * 16;
  const int lofs = srow * LROW + scol * 16;

  // ---- prologue: stage 0 global -> regs -> LDS buf 0 ----
  half8 pr0 = *(const half8*)(gsrc);
  half8 pr1 = *(const half8*)(gsrc + 8);
  float prc = 0.f; int prl = 0;
  if (wave == 0) prc = ce[e0 + lane];
  if (wave == 1) prl = lab_pad[e0 + lane];

  *(half8*)(&Ah[0][lofs])     = pr0;
  *(half8*)(&Ah[0][lofs + 8]) = pr1;
  if (wave == 0) Ce[0][lane] = prc;
  if (wave == 1) Lb[0][lane] = prl;
  __syncthreads();

  floatx4 acc = {0.f, 0.f, 0.f, 0.f};

  #pragma unroll
  for (int st = 0; st < NSTAGE; ++st) {
    const int b = st & 1;

    // prefetch next stage into registers (vmcnt chain, independent of ds_reads)
    if (st + 1 < NSTAGE) {
      const _Float16* g = gsrc + (size_t)(st + 1) * SROWS * KD;
      pr0 = *(const half8*)(g);
      pr1 = *(const half8*)(g + 8);
      if (wave == 0) prc = ce[e0 + (st + 1) * SROWS + lane];
      if (wave == 1) prl = lab_pad[e0 + (st + 1) * SROWS + lane];
    }

    // compute 4 subtiles of 16 e-rows from LDS buf b
    #pragma unroll
    for (int sub = 0; sub < 4; ++sub) {
      const int abase = (sub * 16 + l15) * LROW + quad * 8;
      const half8 ae0 = *(const half8*)(&Ah[b][abase]);
      const half8 ae1 = *(const half8*)(&Ah[b][abase + 32]);
      const float4 ce4 = *(const float4*)(&Ce[b][sub * 16 + quad * 4]);
      const int4   lb4 = *(const int4*)(&Lb[b][sub * 16 + quad * 4]);

      floatx4 d = {0.f, 0.f, 0.f, 0.f};
      d = __builtin_amdgcn_mfma_f32_16x16x32_f16(ae0, bx0, d, 0, 0, 0);
      d = __builtin_amdgcn_mfma_f32_16x16x32_f16(ae1, bx1, d, 0, 0, 0);

      const float cef[4] = { ce4.x, ce4.y, ce4.z, ce4.w };
      half4v p;
      #pragma unroll
      for (int r = 0; r < 4; ++r) {
        const float t = fminf(fmaf(s2, d[r], cbl + cef[r]), 0.f);  // -beta*max(d2,0)
        p[r] = (_Float16)__expf(t);
      }

      half4v oh;
      oh[0] = (lb4.x == l15) ? (_Float16)1.f : (_Float16)0.f;
      oh[1] = (lb4.y == l15) ? (_Float16)1.f : (_Float16)0.f;
      oh[2] = (lb4.z == l15) ? (_Float16)1.f : (_Float16)0.f;
      oh[3] = (lb4.w == l15) ? (_Float16)1.f : (_Float16)0.f;

      acc = __builtin_amdgcn_mfma_f32_16x16x16f16(oh, p, acc, 0, 0, 0);
    }

    if (st + 1 < NSTAGE) {
      __syncthreads();
      const int nb = (st + 1) & 1;
      *(half8*)(&Ah[nb][lofs])     = pr0;
      *(half8*)(&Ah[nb][lofs + 8]) = pr1;
      if (wave == 0) Ce[nb][lane] = prc;
      if (wave == 1) Lb[nb][lane] = prl;
      __syncthreads();
    }
  }

  // Flush: acc holds class_part[c = quad*4+r][b = l15]. Private per-chunk slice,
  // plain stores, zero contention (each cell written by exactly one block).
  float* dst = part + (size_t)chunk * (NB * NC);
  #pragma unroll
  for (int r = 0; r < 4; ++r) {
    const int c = quad * 4 + r;
    if (c < NC) {
      dst[(bm + l15) * NC + c] = acc[r];
    }
  }
}

// ---------------------------------------------------------------------------
// reduce+finalize: out[bc] = log( sum_k part[k][bc] + eps ). Thread bc reads
// part[k][bc] -- consecutive threads hit consecutive addresses (coalesced);
// ~8 MB total, L2/L3-hot. Fixed summation order -> deterministic.
// ---------------------------------------------------------------------------
__global__ __launch_bounds__(256) void reduce_kernel(
    const float* __restrict__ part, float* __restrict__ out)
{
  const int bc = blockIdx.x * 256 + threadIdx.x;
  if (bc < NB * NC) {
    float s = 0.f;
    #pragma unroll 7
    for (int k = 0; k < NCHUNK; ++k) s += part[(size_t)k * (NB * NC) + bc];
    out[bc] = __logf(s + 1e-12f);
  }
}

extern "C" void kernel_launch(void* const* d_in, const int* in_sizes, int n_in,
                              void* d_out, int out_size, void* d_ws, size_t ws_size,
                              hipStream_t stream)
{
  const float* x        = (const float*)d_in[0];
  const float* ex       = (const float*)d_in[1];
  const int*   labels   = (const int*)d_in[2];
  const float* beta_raw = (const float*)d_in[3];
  float* out = (float*)d_out;

  // Workspace layout (~15 MB total):
  char* ws = (char*)d_ws;
  _Float16* ex_h    = (_Float16*)ws;             // 50176*64*2 = 6,422,528 B
  float*    ce      = (float*)(ws + 6422528);    //   200,704 B
  _Float16* x_h     = (_Float16*)(ws + 6623232); //   131,072 B
  float*    cb      = (float*)(ws + 6754304);    //     4,096 B
  int*      lab_pad = (int*)(ws + 6758400);      //   200,704 B
  float*    part    = (float*)(ws + 6959104);    // 196*10240*4 = 8,028,160 B (end: 14,987,264)

  prep_kernel<<<3200, 256, 0, stream>>>(x, ex, labels, beta_raw,
                                        ex_h, ce, x_h, cb, lab_pad);
  dim3 g(16, 196);
  main_kernel<<<g, 256, 0, stream>>>(ex_h, ce, x_h, cb, lab_pad, beta_raw, part);
  reduce_kernel<<<40, 256, 0, stream>>>(part, out);
}